// Round 13
// baseline (111.371 us; speedup 1.0000x reference)
//
#include <hip/hip_runtime.h>

#define WAVLEN   160000
#define NFRAMES  626
#define NFFT     1024
#define HOP      256
#define NSTFT    513
#define NMELS    80
#define WPB      8                 // waves (frames) per block
#define FBLKS    79                // ceil(626/8)
#define PAD(i)   ((i) + ((i) >> 3))
#define BUFSZ    576               // PAD(511)=574 -> round up (float2)
#define PWSTRIDE 52                // floats per packed mel row (mult of 4, 16B rows)
#define PWTOT    (NMELS * PWSTRIDE)   // 4160 floats = 16640 B

__device__ __forceinline__ float2 cadd(float2 a, float2 b){ return make_float2(a.x+b.x, a.y+b.y); }
__device__ __forceinline__ float2 csub(float2 a, float2 b){ return make_float2(a.x-b.x, a.y-b.y); }
__device__ __forceinline__ float2 cmul(float2 a, float2 b){
    return make_float2(fmaf(a.x, b.x, -a.y*b.y), fmaf(a.x, b.y, a.y*b.x));
}
__device__ __forceinline__ float2 mulnegi(float2 a){ return make_float2(a.y, -a.x); } // a * (-i)

__device__ __forceinline__ void fft4(float2& a0, float2& a1, float2& a2, float2& a3) {
    float2 t0 = cadd(a0, a2), t1 = csub(a0, a2);
    float2 t2 = cadd(a1, a3), t3 = csub(a1, a3);
    a0 = cadd(t0, t2); a2 = csub(t0, t2);
    float2 nt3 = mulnegi(t3);
    a1 = cadd(t1, nt3); a3 = csub(t1, nt3);
}

// 8-point DFT, natural in / natural out, no external twiddles.
__device__ __forceinline__ void fft8(float2 v[8]) {
    float2 e0=v[0], e1=v[2], e2=v[4], e3=v[6];
    float2 o0=v[1], o1=v[3], o2=v[5], o3=v[7];
    fft4(e0,e1,e2,e3);
    fft4(o0,o1,o2,o3);
    const float C = 0.70710678118654752f;
    float2 w1o = make_float2(C*(o1.x + o1.y), C*(o1.y - o1.x));   // o1 * c(1-i)
    float2 w2o = mulnegi(o2);                                     // o2 * (-i)
    float2 w3o = make_float2(C*(o3.y - o3.x), -C*(o3.x + o3.y));  // o3 * c(-1-i)
    v[0] = cadd(e0, o0);  v[4] = csub(e0, o0);
    v[1] = cadd(e1, w1o); v[5] = csub(e1, w1o);
    v[2] = cadd(e2, w2o); v[6] = csub(e2, w2o);
    v[3] = cadd(e3, w3o); v[7] = csub(e3, w3o);
}

// Apply w^r, r=1..7, to v[1..7] with a log-depth power tree (dep depth 3).
__device__ __forceinline__ void twiddle7(float2 v[8], float2 b) {
    float2 u2 = cmul(b, b);
    float2 u3 = cmul(u2, b);
    float2 u4 = cmul(u2, u2);
    float2 u5 = cmul(u4, b);
    float2 u6 = cmul(u4, u2);
    float2 u7 = cmul(u4, u3);
    v[1] = cmul(v[1], b);  v[2] = cmul(v[2], u2);
    v[3] = cmul(v[3], u3); v[4] = cmul(v[4], u4);
    v[5] = cmul(v[5], u5); v[6] = cmul(v[6], u6);
    v[7] = cmul(v[7], u7);
}

// Analytic Slaney mel-band support [klo, khi) with +/-1-bin margin.
// Extra bins multiply fb==0, so a conservative range is unconditionally correct.
// MUST be identical in prep and main kernels (deterministic -> same results).
__device__ __forceinline__ int2 mel_range(int m) {
    const float LOGSTEP = 0.06875177742094912f;   // ln(6.4)/27
    const float MSTEP   = 0.55858524f;            // (15 + ln(8)/LOGSTEP)/81
    float mlo = (float)m * MSTEP;
    float mhi = (float)(m + 2) * MSTEP;
    float flo = (mlo < 15.f) ? 66.6666667f * mlo : 1000.f * expf(LOGSTEP * (mlo - 15.f));
    float fhi = (mhi < 15.f) ? 66.6666667f * mhi : 1000.f * expf(LOGSTEP * (mhi - 15.f));
    int klo = (int)(flo * 0.064f) - 1;            // 1/15.625 = 0.064
    int khi = (int)(fhi * 0.064f) + 2;
    klo = max(klo, 0);
    khi = min(khi, NSTFT);
    return make_int2(klo, khi);
}

// Prep: pack fb column m, k = kalo..kalo+PWSTRIDE-1 (kalo = klo&~3) into
// pwg[m*PWSTRIDE + j]. Out-of-triangle entries are genuinely 0 in fb;
// beyond NSTFT we store 0 explicitly.
__global__ __launch_bounds__(1024) void mel_pack_kernel(const float* __restrict__ fb,
                                                        float* __restrict__ pwg) {
    int p = threadIdx.x;
    #pragma unroll
    for (int it = 0; it < 5; ++it, p += 1024) {
        if (p < PWTOT) {
            int m = p / PWSTRIDE, j = p - m * PWSTRIDE;
            int kalo = mel_range(m).x & ~3;
            int k = kalo + j;
            pwg[p] = (k < NSTFT) ? fb[k * NMELS + m] : 0.f;
        }
    }
}

// One wave (64 lanes) per frame; 8 frames per 512-thread block.
// Packed-real 512-pt radix-8 Stockham FFT, in-place per-wave LDS buffer,
// log-depth twiddle powers, float4-vectorized LDS mel projection.
__global__ __launch_bounds__(512) void melspec_kernel(
    const float* __restrict__ wav,     // [B][160000]
    const float* __restrict__ window,  // [1024]
    const float* __restrict__ fb,      // [513][80] (fallback only)
    const float* __restrict__ twr,     // cos(-2pi n/1024), n=0..1023
    const float* __restrict__ twi,     // sin(-2pi n/1024)
    const float* __restrict__ pwg,     // [80*52] packed mel weights (may be null)
    float* __restrict__ out)           // [B][80][626]
{
    __shared__ __align__(16) float2 buf[WPB][BUFSZ];  // 36864 B (sm/pmel overlay)
    __shared__ __align__(16) float  pw[PWTOT];        // 16640 B -> 53504 B total

    const int tid  = threadIdx.x;
    const int lane = tid & 63;
    const int w    = tid >> 6;
    const int b    = blockIdx.x / FBLKS;
    const int fblk = blockIdx.x % FBLKS;
    const int frame = fblk * WPB + w;
    const bool active = frame < NFRAMES;

    // ---- stage packed mel weights into LDS (float4, coalesced) ----
    if (pwg) {
        const float4* pwg4 = (const float4*)pwg;
        float4* pw4 = (float4*)pw;
        for (int p = tid; p < PWTOT / 4; p += 512) pw4[p] = pwg4[p];
    }
    __syncthreads();

    float2* Bf = buf[w];
    float2 v[8];

    if (active) {
        // ---- load + window + fused stage 1 (Ns=1, no twiddles) ----
        const float* wb = wav + (size_t)b * WAVLEN;
        const int base = frame * HOP - 512;
        if (base >= 0 && base + NFFT <= WAVLEN) {
            #pragma unroll
            for (int r = 0; r < 8; ++r) {
                int n = lane + 64 * r;
                float2 s  = *(const float2*)(wb + base + 2 * n);
                float2 wn = *(const float2*)(window + 2 * n);
                v[r] = make_float2(s.x * wn.x, s.y * wn.y);
            }
        } else {
            #pragma unroll
            for (int r = 0; r < 8; ++r) {
                int n = lane + 64 * r;
                int g0 = base + 2 * n, g1 = g0 + 1;
                g0 = g0 < 0 ? -g0 : (g0 >= WAVLEN ? 2 * WAVLEN - 2 - g0 : g0);
                g1 = g1 < 0 ? -g1 : (g1 >= WAVLEN ? 2 * WAVLEN - 2 - g1 : g1);
                v[r] = make_float2(wb[g0] * window[2 * n], wb[g1] * window[2 * n + 1]);
            }
        }
        fft8(v);
        #pragma unroll
        for (int r = 0; r < 8; ++r) Bf[PAD(8 * lane + r)] = v[r];

        // ---- stage 2: Ns=8 ----
        #pragma unroll
        for (int r = 0; r < 8; ++r) v[r] = Bf[PAD(lane + 64 * r)];
        const int jm = lane & 7;
        twiddle7(v, make_float2(twr[16 * jm], twi[16 * jm]));
        fft8(v);
        const int idxD = (lane >> 3) * 64 + jm;
        #pragma unroll
        for (int r = 0; r < 8; ++r) Bf[PAD(idxD + 8 * r)] = v[r];

        // ---- stage 3: Ns=64 ----
        #pragma unroll
        for (int r = 0; r < 8; ++r) v[r] = Bf[PAD(lane + 64 * r)];
        twiddle7(v, make_float2(twr[2 * lane], twi[2 * lane]));
        fft8(v);
        #pragma unroll
        for (int r = 0; r < 8; ++r) Bf[PAD(lane + 64 * r)] = v[r];
        // v[r] still holds Z[lane+64r] -- reused below as zk.

        // ---- Hermitian unpack, register-staged (reads drain before sm writes) ----
        float2 zm[8]; float wrk[8], wik[8];
        #pragma unroll
        for (int r = 0; r < 8; ++r) {
            int k = lane + 64 * r;
            zm[r] = Bf[PAD((512 - k) & 511)];
            wrk[r] = twr[k]; wik[r] = twi[k];   // coalesced
        }
        float* sm = (float*)Bf + 96;            // overlay: floats 96..611 of buf[w]
        #pragma unroll
        for (int r = 0; r < 8; ++r) {
            int k = lane + 64 * r;
            if (k == 0) {
                sm[0]   = fabsf(v[0].x + v[0].y);
                sm[512] = fabsf(v[0].x - v[0].y);
            } else {
                float xer = 0.5f * (v[r].x + zm[r].x), xei = 0.5f * (v[r].y - zm[r].y);
                float xod = 0.5f * (v[r].y + zm[r].y), xoi = 0.5f * (zm[r].x - v[r].x);
                float xr = xer + fmaf(xod, wrk[r], -xoi * wik[r]);
                float xi = xei + fmaf(xod, wik[r],  xoi * wrk[r]);
                sm[k] = sqrtf(fmaf(xr, xr, xi * xi));
            }
        }
        if (lane == 0) { sm[513] = 0.f; sm[514] = 0.f; sm[515] = 0.f; }

        // ---- float4 mel projection; wide mels (16..79) all lanes,
        //      narrow mels (0..15, width<=8) by lanes 0..15 second ----
        float* pmel = (float*)Bf;               // floats 0..79 (disjoint from sm)
        if (pwg) {
            int m = 16 + lane;
            int2 rr = mel_range(m);
            int kalo = rr.x & ~3;
            int nc = (rr.y - kalo + 3) >> 2;    // <= 11; reads sm up to idx 515
            float acc = 0.f;
            const float4* s4 = (const float4*)(sm + kalo);
            const float4* w4 = (const float4*)(pw + m * PWSTRIDE);
            for (int j = 0; j < nc; ++j) {
                float4 s = s4[j], t = w4[j];
                acc = fmaf(s.x, t.x, acc); acc = fmaf(s.y, t.y, acc);
                acc = fmaf(s.z, t.z, acc); acc = fmaf(s.w, t.w, acc);
            }
            pmel[m] = acc;
            if (lane < 16) {
                m = lane;
                rr = mel_range(m);
                kalo = rr.x & ~3;
                nc = (rr.y - kalo + 3) >> 2;    // <= 3
                acc = 0.f;
                const float4* s4b = (const float4*)(sm + kalo);
                const float4* w4b = (const float4*)(pw + m * PWSTRIDE);
                for (int j = 0; j < nc; ++j) {
                    float4 s = s4b[j], t = w4b[j];
                    acc = fmaf(s.x, t.x, acc); acc = fmaf(s.y, t.y, acc);
                    acc = fmaf(s.z, t.z, acc); acc = fmaf(s.w, t.w, acc);
                }
                pmel[m] = acc;
            }
        } else {                                // fallback: direct fb walk
            int m = 16 + lane;
            int2 rr = mel_range(m);
            float acc = 0.f;
            for (int k = rr.x; k < rr.y; ++k)
                acc = fmaf(sm[k], fb[k * NMELS + m], acc);
            pmel[m] = acc;
            if (lane < 16) {
                m = lane;
                rr = mel_range(m);
                acc = 0.f;
                for (int k = rr.x; k < rr.y; ++k)
                    acc = fmaf(sm[k], fb[k * NMELS + m], acc);
                pmel[m] = acc;
            }
        }
    }
    __syncthreads();   // output reads pmel across waves

    // ---- coalesced output: 320 threads write float2 along frame dim ----
    if (tid < 320) {
        int m = tid >> 2, part = tid & 3;
        int f0 = fblk * WPB + 2 * part;
        if (f0 < NFRAMES) {
            float2 o;
            o.x = ((float*)buf[2 * part])[m];
            o.y = ((float*)buf[2 * part + 1])[m];
            *(float2*)(out + ((size_t)b * NMELS + m) * NFRAMES + f0) = o;
        }
    }
}

extern "C" void kernel_launch(void* const* d_in, const int* in_sizes, int n_in,
                              void* d_out, int out_size, void* d_ws, size_t ws_size,
                              hipStream_t stream) {
    const float* wav    = (const float*)d_in[0];
    const float* window = (const float*)d_in[1];
    const float* fb     = (const float*)d_in[2];
    const float* rfr    = (const float*)d_in[3];
    const float* rfi    = (const float*)d_in[4];
    float* out = (float*)d_out;

    float* pwg = nullptr;
    if (ws_size >= PWTOT * sizeof(float)) {
        pwg = (float*)d_ws;
        mel_pack_kernel<<<1, 1024, 0, stream>>>(fb, pwg);
    }

    int B = in_sizes[0] / WAVLEN;            // 32
    melspec_kernel<<<dim3(B * FBLKS), 512, 0, stream>>>(
        wav, window, fb, rfr + NFFT, rfi + NFFT, pwg, out);
}

// Round 15
// 110.422 us; speedup vs baseline: 1.0086x; 1.0086x over previous
//
#include <hip/hip_runtime.h>

#define WAVLEN   160000
#define NFRAMES  626
#define NFFT     1024
#define HOP      256
#define NSTFT    513
#define NMELS    80
#define WPB      8                 // waves (frames) per block
#define FBLKS    79                // ceil(626/8)
#define PAD(i)   ((i) + ((i) >> 3))
#define BUFSZ    584               // PAD(511)=574; +1 slot so lane0 dummy mirror
                                   // read at elem 576 stays in-bounds; 584 keeps
                                   // per-wave stride 16B-aligned (4672 B)
#define PWSTRIDE 52                // floats per packed mel row (mult of 4)
#define PWTOT    (NMELS * PWSTRIDE)   // 4160 floats = 16640 B
#define WS_NEED  ((PWTOT + 2 * NMELS) * 4)

__device__ __forceinline__ float2 cadd(float2 a, float2 b){ return make_float2(a.x+b.x, a.y+b.y); }
__device__ __forceinline__ float2 csub(float2 a, float2 b){ return make_float2(a.x-b.x, a.y-b.y); }
__device__ __forceinline__ float2 cmul(float2 a, float2 b){
    return make_float2(fmaf(a.x, b.x, -a.y*b.y), fmaf(a.x, b.y, a.y*b.x));
}
__device__ __forceinline__ float2 mulnegi(float2 a){ return make_float2(a.y, -a.x); } // a * (-i)

__device__ __forceinline__ void fft4(float2& a0, float2& a1, float2& a2, float2& a3) {
    float2 t0 = cadd(a0, a2), t1 = csub(a0, a2);
    float2 t2 = cadd(a1, a3), t3 = csub(a1, a3);
    a0 = cadd(t0, t2); a2 = csub(t0, t2);
    float2 nt3 = mulnegi(t3);
    a1 = cadd(t1, nt3); a3 = csub(t1, nt3);
}

// 8-point DFT, natural in / natural out, no external twiddles.
__device__ __forceinline__ void fft8(float2 v[8]) {
    float2 e0=v[0], e1=v[2], e2=v[4], e3=v[6];
    float2 o0=v[1], o1=v[3], o2=v[5], o3=v[7];
    fft4(e0,e1,e2,e3);
    fft4(o0,o1,o2,o3);
    const float C = 0.70710678118654752f;
    float2 w1o = make_float2(C*(o1.x + o1.y), C*(o1.y - o1.x));   // o1 * c(1-i)
    float2 w2o = mulnegi(o2);                                     // o2 * (-i)
    float2 w3o = make_float2(C*(o3.y - o3.x), -C*(o3.x + o3.y));  // o3 * c(-1-i)
    v[0] = cadd(e0, o0);  v[4] = csub(e0, o0);
    v[1] = cadd(e1, w1o); v[5] = csub(e1, w1o);
    v[2] = cadd(e2, w2o); v[6] = csub(e2, w2o);
    v[3] = cadd(e3, w3o); v[7] = csub(e3, w3o);
}

// Apply w^r, r=1..7, to v[1..7] with a log-depth power tree (dep depth 3).
__device__ __forceinline__ void twiddle7(float2 v[8], float2 b) {
    float2 u2 = cmul(b, b);
    float2 u3 = cmul(u2, b);
    float2 u4 = cmul(u2, u2);
    float2 u5 = cmul(u4, b);
    float2 u6 = cmul(u4, u2);
    float2 u7 = cmul(u4, u3);
    v[1] = cmul(v[1], b);  v[2] = cmul(v[2], u2);
    v[3] = cmul(v[3], u3); v[4] = cmul(v[4], u4);
    v[5] = cmul(v[5], u5); v[6] = cmul(v[6], u6);
    v[7] = cmul(v[7], u7);
}

// Analytic Slaney mel-band support [klo, khi) with +/-1-bin margin.
// Extra bins multiply fb==0, so a conservative range is unconditionally correct.
__device__ __forceinline__ int2 mel_range(int m) {
    const float LOGSTEP = 0.06875177742094912f;   // ln(6.4)/27
    const float MSTEP   = 0.55858524f;            // (15 + ln(8)/LOGSTEP)/81
    float mlo = (float)m * MSTEP;
    float mhi = (float)(m + 2) * MSTEP;
    float flo = (mlo < 15.f) ? 66.6666667f * mlo : 1000.f * expf(LOGSTEP * (mlo - 15.f));
    float fhi = (mhi < 15.f) ? 66.6666667f * mhi : 1000.f * expf(LOGSTEP * (mhi - 15.f));
    int klo = (int)(flo * 0.064f) - 1;            // 1/15.625 = 0.064
    int khi = (int)(fhi * 0.064f) + 2;
    klo = max(klo, 0);
    khi = min(khi, NSTFT);
    return make_int2(klo, khi);
}

// Prep: pack fb column m (k from kalo = klo&~3, PWSTRIDE wide) into pwg, and
// store per-mel int2(kalo, nchunks) after the weights (main kernel does zero
// range arithmetic).
__global__ __launch_bounds__(1024) void mel_pack_kernel(const float* __restrict__ fb,
                                                        float* __restrict__ pwg) {
    int p = threadIdx.x;
    #pragma unroll
    for (int it = 0; it < 5; ++it, p += 1024) {
        if (p < PWTOT) {
            int m = p / PWSTRIDE, j = p - m * PWSTRIDE;
            int kalo = mel_range(m).x & ~3;
            int k = kalo + j;
            pwg[p] = (k < NSTFT) ? fb[k * NMELS + m] : 0.f;
        }
    }
    int m = threadIdx.x;
    if (m < NMELS) {
        int2 rr = mel_range(m);
        int kalo = rr.x & ~3;
        int nc = (rr.y - kalo + 3) >> 2;          // <= 11
        ((int2*)(pwg + PWTOT))[m] = make_int2(kalo, nc);
    }
}

// One wave (64 lanes) per frame; 8 frames per 512-thread block.
// Packed-real 512-pt radix-8 Stockham FFT, in-place per-wave LDS buffer.
// All LDS addresses are one base register + ds immediate offsets:
//   PAD(lane+64r) = pb + 72r            (pb = lane + (lane>>3))
//   PAD(8*lane+r) = 9*lane + r
//   PAD(idxD+8r)  = 72*(lane>>3)+jm + 9r
//   PAD(mirror)   = pz + 72*(7-r)       (pz = PAD(64-lane))
__global__ __launch_bounds__(512) void melspec_kernel(
    const float* __restrict__ wav,     // [B][160000]
    const float* __restrict__ window,  // [1024]
    const float* __restrict__ fb,      // [513][80] (fallback only)
    const float* __restrict__ twr,     // cos(-2pi n/1024), n=0..1023
    const float* __restrict__ twi,     // sin(-2pi n/1024)
    const float* __restrict__ pwg,     // packed weights + int2 ranges (may be null)
    float* __restrict__ out)           // [B][80][626]
{
    __shared__ __align__(16) float2 buf[WPB][BUFSZ];  // 37376 B (sm/pmel overlay)
    __shared__ __align__(16) float  pw[PWTOT];        // 16640 B
    __shared__ int2 rngs[NMELS];                      // 640 B -> 54656 B total

    const int tid  = threadIdx.x;
    const int lane = tid & 63;
    const int w    = tid >> 6;
    const int b    = blockIdx.x / FBLKS;
    const int fblk = blockIdx.x % FBLKS;
    const int frame = fblk * WPB + w;
    const bool active = frame < NFRAMES;

    // ---- stage packed mel weights + ranges into LDS ----
    if (pwg) {
        const float4* pwg4 = (const float4*)pwg;
        float4* pw4 = (float4*)pw;
        for (int p = tid; p < PWTOT / 4; p += 512) pw4[p] = pwg4[p];
        if (tid < NMELS) rngs[tid] = ((const int2*)(pwg + PWTOT))[tid];
    }
    __syncthreads();

    float2* Bf = buf[w];
    float2 v[8];
    const int pb = lane + (lane >> 3);

    if (active) {
        // ---- load + window + fused stage 1 (Ns=1, no twiddles) ----
        const float* wb = wav + (size_t)b * WAVLEN;
        const int base = frame * HOP - 512;
        if (base >= 0 && base + NFFT <= WAVLEN) {
            #pragma unroll
            for (int r = 0; r < 8; ++r) {
                int n = lane + 64 * r;
                float2 s  = *(const float2*)(wb + base + 2 * n);
                float2 wn = *(const float2*)(window + 2 * n);
                v[r] = make_float2(s.x * wn.x, s.y * wn.y);
            }
        } else {
            #pragma unroll
            for (int r = 0; r < 8; ++r) {
                int n = lane + 64 * r;
                int g0 = base + 2 * n, g1 = g0 + 1;
                g0 = g0 < 0 ? -g0 : (g0 >= WAVLEN ? 2 * WAVLEN - 2 - g0 : g0);
                g1 = g1 < 0 ? -g1 : (g1 >= WAVLEN ? 2 * WAVLEN - 2 - g1 : g1);
                v[r] = make_float2(wb[g0] * window[2 * n], wb[g1] * window[2 * n + 1]);
            }
        }
        fft8(v);
        {
            const int p1 = 9 * lane;
            #pragma unroll
            for (int r = 0; r < 8; ++r) Bf[p1 + r] = v[r];
        }

        // ---- stage 2: Ns=8 ----
        #pragma unroll
        for (int r = 0; r < 8; ++r) v[r] = Bf[pb + 72 * r];
        const int jm = lane & 7;
        twiddle7(v, make_float2(twr[16 * jm], twi[16 * jm]));
        fft8(v);
        {
            const int p2 = 72 * (lane >> 3) + jm;
            #pragma unroll
            for (int r = 0; r < 8; ++r) Bf[p2 + 9 * r] = v[r];
        }

        // ---- stage 3: Ns=64 ----
        #pragma unroll
        for (int r = 0; r < 8; ++r) v[r] = Bf[pb + 72 * r];
        twiddle7(v, make_float2(twr[2 * lane], twi[2 * lane]));
        fft8(v);
        #pragma unroll
        for (int r = 0; r < 8; ++r) Bf[pb + 72 * r] = v[r];
        // v[r] still holds Z[lane+64r] -- reused below as zk.

        // ---- Hermitian unpack, register-staged; 0.5 factored into sqrt ----
        float2 zm[8]; float wrk[8], wik[8];
        {
            int pzl = 64 - lane;
            const int pz = pzl + (pzl >> 3);      // lane0: 72 (dummy slot 576 ok)
            #pragma unroll
            for (int r = 0; r < 8; ++r) {
                zm[r] = Bf[pz + 72 * (7 - r)];
                int k = lane + 64 * r;
                wrk[r] = twr[k]; wik[r] = twi[k]; // coalesced
            }
        }
        float* sm = (float*)Bf + 96;              // overlay: floats 96..611
        #pragma unroll
        for (int r = 0; r < 8; ++r) {
            int k = lane + 64 * r;
            if (k == 0) {
                sm[0]   = fabsf(v[0].x + v[0].y);
                sm[512] = fabsf(v[0].x - v[0].y);
            } else {
                float xer = v[r].x + zm[r].x, xei = v[r].y - zm[r].y;
                float xod = v[r].y + zm[r].y, xoi = zm[r].x - v[r].x;
                float xr = xer + fmaf(xod, wrk[r], -xoi * wik[r]);
                float xi = xei + fmaf(xod, wik[r],  xoi * wrk[r]);
                sm[k] = 0.5f * sqrtf(fmaf(xr, xr, xi * xi));
            }
        }
        if (lane == 0) { sm[513] = 0.f; sm[514] = 0.f; sm[515] = 0.f; }

        // ---- float4 mel projection; wide mels (16..79) all lanes,
        //      narrow mels (0..15) by lanes 0..15 second ----
        float* pmel = (float*)Bf;                 // floats 0..79 (disjoint from sm)
        if (pwg) {
            int m = 16 + lane;
            int2 rr = rngs[m];                    // (kalo, nchunks)
            float acc = 0.f;
            const float4* s4 = (const float4*)(sm + rr.x);
            const float4* w4 = (const float4*)(pw + m * PWSTRIDE);
            for (int j = 0; j < rr.y; ++j) {
                float4 s = s4[j], t = w4[j];
                acc = fmaf(s.x, t.x, acc); acc = fmaf(s.y, t.y, acc);
                acc = fmaf(s.z, t.z, acc); acc = fmaf(s.w, t.w, acc);
            }
            pmel[m] = acc;
            if (lane < 16) {
                m = lane;
                rr = rngs[m];
                acc = 0.f;
                const float4* s4b = (const float4*)(sm + rr.x);
                const float4* w4b = (const float4*)(pw + m * PWSTRIDE);
                for (int j = 0; j < rr.y; ++j) {
                    float4 s = s4b[j], t = w4b[j];
                    acc = fmaf(s.x, t.x, acc); acc = fmaf(s.y, t.y, acc);
                    acc = fmaf(s.z, t.z, acc); acc = fmaf(s.w, t.w, acc);
                }
                pmel[m] = acc;
            }
        } else {                                  // fallback: direct fb walk
            int m = 16 + lane;
            int2 rr = mel_range(m);
            float acc = 0.f;
            for (int k = rr.x; k < rr.y; ++k)
                acc = fmaf(sm[k], fb[k * NMELS + m], acc);
            pmel[m] = acc;
            if (lane < 16) {
                m = lane;
                rr = mel_range(m);
                acc = 0.f;
                for (int k = rr.x; k < rr.y; ++k)
                    acc = fmaf(sm[k], fb[k * NMELS + m], acc);
                pmel[m] = acc;
            }
        }
    }
    __syncthreads();   // output reads pmel across waves

    // ---- coalesced output: 320 threads write float2 along frame dim ----
    if (tid < 320) {
        int m = tid >> 2, part = tid & 3;
        int f0 = fblk * WPB + 2 * part;
        if (f0 < NFRAMES) {
            float2 o;
            o.x = ((float*)buf[2 * part])[m];
            o.y = ((float*)buf[2 * part + 1])[m];
            *(float2*)(out + ((size_t)b * NMELS + m) * NFRAMES + f0) = o;
        }
    }
}

extern "C" void kernel_launch(void* const* d_in, const int* in_sizes, int n_in,
                              void* d_out, int out_size, void* d_ws, size_t ws_size,
                              hipStream_t stream) {
    const float* wav    = (const float*)d_in[0];
    const float* window = (const float*)d_in[1];
    const float* fb     = (const float*)d_in[2];
    const float* rfr    = (const float*)d_in[3];
    const float* rfi    = (const float*)d_in[4];
    float* out = (float*)d_out;

    float* pwg = nullptr;
    if (ws_size >= WS_NEED) {
        pwg = (float*)d_ws;
        mel_pack_kernel<<<1, 1024, 0, stream>>>(fb, pwg);
    }

    int B = in_sizes[0] / WAVLEN;            // 32
    melspec_kernel<<<dim3(B * FBLKS), 512, 0, stream>>>(
        wav, window, fb, rfr + NFFT, rfi + NFFT, pwg, out);
}